// Round 12
// baseline (603.881 us; speedup 1.0000x reference)
//
#include <hip/hip_runtime.h>
#include <hip/hip_fp16.h>

#define DIM 64
#define PSHIFT 14            // panel = idx >> 14 : 8 panels x 16384 nodes (2MB fp16)
#define NPAN 8
#define SWEEP_BLOCKS 1024    // 4 blocks/CU, co-resident
#define MAX_RPB 112          // max rows per block (LDS tile bound)
#define TSTRIDE 68           // f32 stride per tile row (16B-aligned, bank-spread)

// ---------- pass 1: compress x (f32) -> xh (fp16) ----------
__global__ __launch_bounds__(256) void cvt_half_kernel(
    const float* __restrict__ x, __half* __restrict__ xh, int n4)
{
    int i = blockIdx.x * blockDim.x + threadIdx.x;
    const int stride = gridDim.x * blockDim.x;
    for (; i < n4; i += stride) {
        const float4 v = ((const float4*)x)[i];
        __half2 h0 = __floats2half2_rn(v.x, v.y);
        __half2 h1 = __floats2half2_rn(v.z, v.w);
        uint2 u;
        u.x = *(const unsigned int*)&h0;
        u.y = *(const unsigned int*)&h1;
        ((uint2*)xh)[i] = u;
    }
}

// ---------- pass 2: per-block counting sort of edges by panel ----------
// Block owns rows [b*rows_pb, ...). Sorts its edge range by panel (unstable
// within panel -- only fp sum order changes). spair = ((rowlocal<<17)|idx, val).
__global__ __launch_bounds__(256) void bucket2_kernel(
    const int*   __restrict__ indptr,
    const int*   __restrict__ indices,
    const float* __restrict__ values,
    uint2*       __restrict__ spair,
    int n_nodes, int rows_pb)
{
    __shared__ int rptr[MAX_RPB + 1];
    __shared__ int cnt[NPAN];
    __shared__ int cur[NPAN];

    const int b   = blockIdx.x;
    const int tid = (int)threadIdx.x;
    const int rbase = b * rows_pb;
    if (rbase >= n_nodes) return;
    int nrows = n_nodes - rbase; if (nrows > rows_pb) nrows = rows_pb;

    for (int i = tid; i <= nrows; i += 256) rptr[i] = indptr[rbase + i];
    if (tid < NPAN) cnt[tid] = 0;
    __syncthreads();

    const int ebase = rptr[0];
    const int eend  = rptr[nrows];

    for (int e = ebase + tid; e < eend; e += 256)
        atomicAdd(&cnt[indices[e] >> PSHIFT], 1);
    __syncthreads();
    if (tid == 0) {
        int acc = 0;
        for (int p = 0; p < NPAN; ++p) { cur[p] = acc; acc += cnt[p]; }
    }
    __syncthreads();

    for (int e = ebase + tid; e < eend; e += 256) {
        const int   idx = indices[e];
        const float v   = values[e];
        const int   p   = idx >> PSHIFT;
        // rowlocal: largest r with rptr[r] <= e  (7-step bsearch in LDS)
        int lo = 0, hi = nrows - 1;
        while (lo < hi) {
            const int mid = (lo + hi + 1) >> 1;
            if (rptr[mid] <= e) lo = mid; else hi = mid - 1;
        }
        const int pos = atomicAdd(&cur[p], 1);
        uint2 pr;
        pr.x = ((unsigned)lo << 17) | (unsigned)idx;
        pr.y = __float_as_uint(v);
        spair[ebase + pos] = pr;
    }
}

// ---------- pass 3: panel sweep with LDS row-tile accumulators ----------
// Block streams its panel-sorted edges in rounds of 64 (4 waves x 16 edges,
// 8 lanes/edge, 2-stage pipeline -> 32 lines in flight per wave). Each edge
// accumulates into the block's LDS tile via ds_add_f32. All blocks sweep
// panels in phase -> gathers hit a sliding ~2MB XCD-L2-resident band.
__global__ __launch_bounds__(256, 4) void sweep2_kernel(
    const __half* __restrict__ xh,
    const int*    __restrict__ indptr,
    const uint2*  __restrict__ spair,
    float*        __restrict__ out,
    int n_nodes, int rows_pb)
{
    __shared__ float tile[MAX_RPB * TSTRIDE];

    const int b   = blockIdx.x;
    const int tid = (int)threadIdx.x;
    const int rbase = b * rows_pb;
    if (rbase >= n_nodes) return;
    int nrows = n_nodes - rbase; if (nrows > rows_pb) nrows = rows_pb;

    for (int i = tid; i < nrows * TSTRIDE; i += 256) tile[i] = 0.f;

    const int ebase = indptr[rbase];
    const int eend  = indptr[rbase + nrows];
    const int L     = eend - ebase;
    __syncthreads();

    const int wv   = tid >> 6;       // wave 0..3
    const int lane = tid & 63;
    const int g    = lane >> 3;      // edge sub-slot 0..7
    const int t    = lane & 7;       // column octet

#define LOADSTAGE(E0, E1, PK0, PK1, G0, G1, V0, V1)                        \
    {                                                                      \
        V0 = (E0) < L; V1 = (E1) < L;                                      \
        const int a0 = V0 ? (E0) : 0;                                      \
        const int a1 = V1 ? (E1) : 0;                                      \
        PK0 = spair[ebase + a0]; PK1 = spair[ebase + a1];                  \
        const unsigned c0 = PK0.x & 0x1FFFFu;                              \
        const unsigned c1 = PK1.x & 0x1FFFFu;                              \
        G0 = *(const uint4*)(xh + ((size_t)c0 << 6) + (t << 3));           \
        G1 = *(const uint4*)(xh + ((size_t)c1 << 6) + (t << 3));           \
    }

#define DSADD(PK, G, V)                                                    \
    if (V) {                                                               \
        const float vv = __uint_as_float((PK).y);                          \
        float* rowp = &tile[(int)((PK).x >> 17) * TSTRIDE + (t << 3)];     \
        const __half* h = (const __half*)&(G);                             \
        _Pragma("unroll")                                                  \
        for (int j = 0; j < 8; ++j)                                        \
            atomicAdd(rowp + j, __half2float(h[j]) * vv);                  \
    }

    // round r: wave wv handles edges r*64 + wv*16 + {g, 8+g}
    uint2 pkA0, pkA1; uint4 gA0, gA1; bool vA0, vA1;
    LOADSTAGE(wv * 16 + g, wv * 16 + 8 + g, pkA0, pkA1, gA0, gA1, vA0, vA1)

    for (int base = 0; base < L; base += 64) {
        uint2 pkB0, pkB1; uint4 gB0, gB1; bool vB0, vB1;
        const int n0 = base + 64 + wv * 16 + g;
        LOADSTAGE(n0, n0 + 8, pkB0, pkB1, gB0, gB1, vB0, vB1)
        DSADD(pkA0, gA0, vA0)
        DSADD(pkA1, gA1, vA1)
        pkA0 = pkB0; pkA1 = pkB1;
        gA0  = gB0;  gA1  = gB1;
        vA0  = vB0;  vA1  = vB1;
    }
#undef LOADSTAGE
#undef DSADD

    __syncthreads();
    // coalesced tile -> out
    for (int i = tid; i < nrows * DIM; i += 256) {
        const int r = i >> 6, c = i & 63;
        out[((size_t)(rbase + r) << 6) + c] = tile[r * TSTRIDE + c];
    }
}

// ---------- champion fallback: unsorted fp16, one row per wave ----------
__global__ __launch_bounds__(256) void spmm_half_kernel(
    const __half* __restrict__ xh,
    const int*   __restrict__ indptr,
    const int*   __restrict__ indices,
    const float* __restrict__ values,
    float*       __restrict__ out,
    int n_nodes)
{
    const int row  = (int)((blockIdx.x * blockDim.x + threadIdx.x) >> 6);
    const int lane = (int)(threadIdx.x & 63);
    if (row >= n_nodes) return;
    const int g = lane >> 3;
    const int t = lane & 7;

    const int start = indptr[row];
    const int end   = indptr[row + 1];

    float a[8] = {0.f,0.f,0.f,0.f,0.f,0.f,0.f,0.f};

    if (start < end) {
        const int last = end - 1;
        for (int k = start; k < end; k += 16) {
            const int e0 = k + g;
            const int e1 = k + 8 + g;
            const int i0 = (e0 <= last) ? e0 : last;
            const int i1 = (e1 <= last) ? e1 : last;
            const int c0 = indices[i0];
            const int c1 = indices[i1];
            const float w0 = (e0 <= last) ? values[i0] : 0.0f;
            const float w1 = (e1 <= last) ? values[i1] : 0.0f;
            const uint4 p0 = *(const uint4*)(xh + (((unsigned)c0) << 6) + (t << 3));
            const uint4 p1 = *(const uint4*)(xh + (((unsigned)c1) << 6) + (t << 3));
            const __half* h0 = (const __half*)&p0;
            const __half* h1 = (const __half*)&p1;
#pragma unroll
            for (int j = 0; j < 8; ++j) a[j] += __half2float(h0[j]) * w0;
#pragma unroll
            for (int j = 0; j < 8; ++j) a[j] += __half2float(h1[j]) * w1;
        }
    }

#define RED(m) a[0]+=__shfl_xor(a[0],m); a[1]+=__shfl_xor(a[1],m); \
               a[2]+=__shfl_xor(a[2],m); a[3]+=__shfl_xor(a[3],m); \
               a[4]+=__shfl_xor(a[4],m); a[5]+=__shfl_xor(a[5],m); \
               a[6]+=__shfl_xor(a[6],m); a[7]+=__shfl_xor(a[7],m);
    RED(8) RED(16) RED(32)
#undef RED

    if (lane < 8) {
        float4 r0; r0.x=a[0]; r0.y=a[1]; r0.z=a[2]; r0.w=a[3];
        float4 r1; r1.x=a[4]; r1.y=a[5]; r1.z=a[6]; r1.w=a[7];
        float* dst = out + (((size_t)row) << 6) + (t << 3);
        *(float4*)(dst)     = r0;
        *(float4*)(dst + 4) = r1;
    }
}

// ---------- f32 fallback (ws too small) ----------
__global__ __launch_bounds__(256) void spmm_quad_kernel(
    const float* __restrict__ x,
    const int*   __restrict__ indptr,
    const int*   __restrict__ indices,
    const float* __restrict__ values,
    float*       __restrict__ out,
    int n_nodes)
{
    const int row  = (int)((blockIdx.x * blockDim.x + threadIdx.x) >> 6);
    const int lane = (int)(threadIdx.x & 63);
    if (row >= n_nodes) return;

    const int start = indptr[row];
    const int end   = indptr[row + 1];
    const int g     = lane >> 4;
    const unsigned col4 = (unsigned)(lane & 15) << 2;

    float ax = 0.f, ay = 0.f, az = 0.f, aw = 0.f;

    if (start < end) {
        const int last = end - 1;
        for (int k = start; k < end; k += 16) {
            const int e0 = k + 0 + g, e1 = k + 4 + g, e2 = k + 8 + g, e3 = k + 12 + g;
            const int ce0 = e0 <= last ? e0 : last;
            const int ce1 = e1 <= last ? e1 : last;
            const int ce2 = e2 <= last ? e2 : last;
            const int ce3 = e3 <= last ? e3 : last;
            const int c0 = indices[ce0], c1 = indices[ce1];
            const int c2 = indices[ce2], c3 = indices[ce3];
            const float w0 = (e0 <= last) ? values[ce0] : 0.0f;
            const float w1 = (e1 <= last) ? values[ce1] : 0.0f;
            const float w2 = (e2 <= last) ? values[ce2] : 0.0f;
            const float w3 = (e3 <= last) ? values[ce3] : 0.0f;
            const float4 a0 = *(const float4*)(x + (((unsigned)c0) << 6) + col4);
            const float4 a1 = *(const float4*)(x + (((unsigned)c1) << 6) + col4);
            const float4 a2 = *(const float4*)(x + (((unsigned)c2) << 6) + col4);
            const float4 a3 = *(const float4*)(x + (((unsigned)c3) << 6) + col4);
            ax += w0 * a0.x; ay += w0 * a0.y; az += w0 * a0.z; aw += w0 * a0.w;
            ax += w1 * a1.x; ay += w1 * a1.y; az += w1 * a1.z; aw += w1 * a1.w;
            ax += w2 * a2.x; ay += w2 * a2.y; az += w2 * a2.z; aw += w2 * a2.w;
            ax += w3 * a3.x; ay += w3 * a3.y; az += w3 * a3.z; aw += w3 * a3.w;
        }
    }

    ax += __shfl_xor(ax, 16); ay += __shfl_xor(ay, 16);
    az += __shfl_xor(az, 16); aw += __shfl_xor(aw, 16);
    ax += __shfl_xor(ax, 32); ay += __shfl_xor(ay, 32);
    az += __shfl_xor(az, 32); aw += __shfl_xor(aw, 32);

    if (lane < 16) {
        float4 r; r.x = ax; r.y = ay; r.z = az; r.w = aw;
        *(float4*)(out + ((size_t)row << 6) + col4) = r;
    }
}

extern "C" void kernel_launch(void* const* d_in, const int* in_sizes, int n_in,
                              void* d_out, int out_size, void* d_ws, size_t ws_size,
                              hipStream_t stream) {
    const float* x       = (const float*)d_in[0];
    const int*   indptr  = (const int*)  d_in[1];
    const int*   indices = (const int*)  d_in[2];
    const float* values  = (const float*)d_in[3];
    float*       out     = (float*)d_out;

    const int n_nodes = in_sizes[1] - 1;     // indptr has N+1 entries
    const int n_xelem = in_sizes[0];         // N * 64
    const int n_edges = in_sizes[2];

    const int threads = 256;
    const int rows_pb = (n_nodes + SWEEP_BLOCKS - 1) / SWEEP_BLOCKS;

    const size_t xh_bytes    = (size_t)n_xelem * sizeof(__half);
    const size_t spair_bytes = (size_t)n_edges * sizeof(uint2);

    const bool sweep_ok = (ws_size >= xh_bytes + spair_bytes) &&
                          (n_nodes <= (1 << 17)) &&     // idx fits 17 bits
                          (rows_pb <= MAX_RPB);

    if (sweep_ok) {
        __half* xh    = (__half*)d_ws;
        uint2*  spair = (uint2*)((char*)d_ws + xh_bytes);

        cvt_half_kernel<<<2048, threads, 0, stream>>>(x, xh, n_xelem / 4);
        bucket2_kernel<<<SWEEP_BLOCKS, threads, 0, stream>>>(
            indptr, indices, values, spair, n_nodes, rows_pb);
        sweep2_kernel<<<SWEEP_BLOCKS, threads, 0, stream>>>(
            xh, indptr, spair, out, n_nodes, rows_pb);
    } else if (ws_size >= xh_bytes) {
        __half* xh = (__half*)d_ws;
        cvt_half_kernel<<<2048, threads, 0, stream>>>(x, xh, n_xelem / 4);
        const int row_blocks = (n_nodes + 3) / 4;
        spmm_half_kernel<<<row_blocks, threads, 0, stream>>>(
            xh, indptr, indices, values, out, n_nodes);
    } else {
        const int row_blocks = (n_nodes + 3) / 4;
        spmm_quad_kernel<<<row_blocks, threads, 0, stream>>>(
            x, indptr, indices, values, out, n_nodes);
    }
}

// Round 14
// 65.237 us; speedup vs baseline: 9.2567x; 9.2567x over previous
//
#include <hip/hip_runtime.h>
#include <hip/hip_fp16.h>

#define DIM 64

typedef float  fv4 __attribute__((ext_vector_type(4)));   // native vec for nontemporal builtins
typedef unsigned int uv4 __attribute__((ext_vector_type(4)));

// ---------- pass 1: compress x (f32) -> xh (fp16) in workspace ----------
// x is read once (nontemporal); xh is re-read heavily by the SpMM (temporal store).
__global__ __launch_bounds__(256) void cvt_half_kernel(
    const float* __restrict__ x, __half* __restrict__ xh, int n4)
{
    int i = blockIdx.x * blockDim.x + threadIdx.x;
    const int stride = gridDim.x * blockDim.x;
    for (; i < n4; i += stride) {
        const fv4 v = __builtin_nontemporal_load(((const fv4*)x) + i);
        __half2 h0 = __floats2half2_rn(v.x, v.y);
        __half2 h1 = __floats2half2_rn(v.z, v.w);
        uint2 u;
        u.x = *(const unsigned int*)&h0;
        u.y = *(const unsigned int*)&h1;
        ((uint2*)xh)[i] = u;
    }
}

// ---------- pass 2: CSR SpMM over fp16 x (champion structure) ----------
// One wave per row. 8 groups x 8 lanes; group g owns edge slots k+g and
// k+8+g; lane reads 16B (8 halves) of that edge's x-row -> one dwordx4
// moves 8 edges' rows (1 KiB, 1 cache line per edge). Indices clamped to
// the row's own last edge (duplicate gathers coalesce to the same line).
// Edge-list loads and out stores are nontemporal: they are streamed once,
// keeping L2 capacity for the hot xh gather working set.
__global__ __launch_bounds__(256) void spmm_half_kernel(
    const __half* __restrict__ xh,
    const int*   __restrict__ indptr,
    const int*   __restrict__ indices,
    const float* __restrict__ values,
    float*       __restrict__ out,
    int n_nodes)
{
    const int row  = (int)((blockIdx.x * blockDim.x + threadIdx.x) >> 6);
    const int lane = (int)(threadIdx.x & 63);
    if (row >= n_nodes) return;
    const int g = lane >> 3;        // edge slot 0..7
    const int t = lane & 7;         // column octet: cols [t*8, t*8+8)

    const int start = indptr[row];
    const int end   = indptr[row + 1];

    float a[8] = {0.f,0.f,0.f,0.f,0.f,0.f,0.f,0.f};

    if (start < end) {
        const int last = end - 1;
        for (int k = start; k < end; k += 16) {
            const int e0 = k + g;
            const int e1 = k + 8 + g;
            const int i0 = (e0 <= last) ? e0 : last;
            const int i1 = (e1 <= last) ? e1 : last;
            const int c0 = __builtin_nontemporal_load(indices + i0);
            const int c1 = __builtin_nontemporal_load(indices + i1);
            const float v0 = __builtin_nontemporal_load(values + i0);
            const float v1 = __builtin_nontemporal_load(values + i1);
            const float w0 = (e0 <= last) ? v0 : 0.0f;
            const float w1 = (e1 <= last) ? v1 : 0.0f;

            const uint4 p0 = *(const uint4*)(xh + (((unsigned)c0) << 6) + (t << 3));
            const uint4 p1 = *(const uint4*)(xh + (((unsigned)c1) << 6) + (t << 3));

            const __half* h0 = (const __half*)&p0;
            const __half* h1 = (const __half*)&p1;
#pragma unroll
            for (int j = 0; j < 8; ++j) a[j] += __half2float(h0[j]) * w0;
#pragma unroll
            for (int j = 0; j < 8; ++j) a[j] += __half2float(h1[j]) * w1;
        }
    }

    // Sum the 8 edge-groups: lanes {l^8, l^16, l^32} hold the same columns.
#define RED(m) a[0]+=__shfl_xor(a[0],m); a[1]+=__shfl_xor(a[1],m); \
               a[2]+=__shfl_xor(a[2],m); a[3]+=__shfl_xor(a[3],m); \
               a[4]+=__shfl_xor(a[4],m); a[5]+=__shfl_xor(a[5],m); \
               a[6]+=__shfl_xor(a[6],m); a[7]+=__shfl_xor(a[7],m);
    RED(8) RED(16) RED(32)
#undef RED

    if (lane < 8) {
        fv4 r0; r0.x=a[0]; r0.y=a[1]; r0.z=a[2]; r0.w=a[3];
        fv4 r1; r1.x=a[4]; r1.y=a[5]; r1.z=a[6]; r1.w=a[7];
        float* dst = out + (((size_t)row) << 6) + (t << 3);
        __builtin_nontemporal_store(r0, (fv4*)(dst));
        __builtin_nontemporal_store(r1, (fv4*)(dst + 4));
    }
}

// ---------- f32 fallback (ws too small): round-3 quad kernel ----------
__global__ __launch_bounds__(256) void spmm_quad_kernel(
    const float* __restrict__ x,
    const int*   __restrict__ indptr,
    const int*   __restrict__ indices,
    const float* __restrict__ values,
    float*       __restrict__ out,
    int n_nodes)
{
    const int row  = (int)((blockIdx.x * blockDim.x + threadIdx.x) >> 6);
    const int lane = (int)(threadIdx.x & 63);
    if (row >= n_nodes) return;

    const int start = indptr[row];
    const int end   = indptr[row + 1];
    const int g     = lane >> 4;
    const unsigned col4 = (unsigned)(lane & 15) << 2;

    float ax = 0.f, ay = 0.f, az = 0.f, aw = 0.f;

    if (start < end) {
        const int last = end - 1;
        for (int k = start; k < end; k += 16) {
            const int e0 = k + 0 + g, e1 = k + 4 + g, e2 = k + 8 + g, e3 = k + 12 + g;
            const int ce0 = e0 <= last ? e0 : last;
            const int ce1 = e1 <= last ? e1 : last;
            const int ce2 = e2 <= last ? e2 : last;
            const int ce3 = e3 <= last ? e3 : last;
            const int c0 = indices[ce0], c1 = indices[ce1];
            const int c2 = indices[ce2], c3 = indices[ce3];
            const float w0 = (e0 <= last) ? values[ce0] : 0.0f;
            const float w1 = (e1 <= last) ? values[ce1] : 0.0f;
            const float w2 = (e2 <= last) ? values[ce2] : 0.0f;
            const float w3 = (e3 <= last) ? values[ce3] : 0.0f;
            const float4 a0 = *(const float4*)(x + (((unsigned)c0) << 6) + col4);
            const float4 a1 = *(const float4*)(x + (((unsigned)c1) << 6) + col4);
            const float4 a2 = *(const float4*)(x + (((unsigned)c2) << 6) + col4);
            const float4 a3 = *(const float4*)(x + (((unsigned)c3) << 6) + col4);
            ax += w0 * a0.x; ay += w0 * a0.y; az += w0 * a0.z; aw += w0 * a0.w;
            ax += w1 * a1.x; ay += w1 * a1.y; az += w1 * a1.z; aw += w1 * a1.w;
            ax += w2 * a2.x; ay += w2 * a2.y; az += w2 * a2.z; aw += w2 * a2.w;
            ax += w3 * a3.x; ay += w3 * a3.y; az += w3 * a3.z; aw += w3 * a3.w;
        }
    }

    ax += __shfl_xor(ax, 16); ay += __shfl_xor(ay, 16);
    az += __shfl_xor(az, 16); aw += __shfl_xor(aw, 16);
    ax += __shfl_xor(ax, 32); ay += __shfl_xor(ay, 32);
    az += __shfl_xor(az, 32); aw += __shfl_xor(aw, 32);

    if (lane < 16) {
        float4 r; r.x = ax; r.y = ay; r.z = az; r.w = aw;
        *(float4*)(out + ((size_t)row << 6) + col4) = r;
    }
}

extern "C" void kernel_launch(void* const* d_in, const int* in_sizes, int n_in,
                              void* d_out, int out_size, void* d_ws, size_t ws_size,
                              hipStream_t stream) {
    const float* x       = (const float*)d_in[0];
    const int*   indptr  = (const int*)  d_in[1];
    const int*   indices = (const int*)  d_in[2];
    const float* values  = (const float*)d_in[3];
    float*       out     = (float*)d_out;

    const int n_nodes = in_sizes[1] - 1;     // indptr has N+1 entries
    const int n_xelem = in_sizes[0];         // N * 64

    const int threads = 256;
    const int row_blocks = (n_nodes + 3) / 4;    // 4 waves/block, 1 row/wave

    const size_t xh_bytes = (size_t)n_xelem * sizeof(__half);
    if (ws_size >= xh_bytes) {
        __half* xh = (__half*)d_ws;
        cvt_half_kernel<<<2048, threads, 0, stream>>>(x, xh, n_xelem / 4);
        spmm_half_kernel<<<row_blocks, threads, 0, stream>>>(
            xh, indptr, indices, values, out, n_nodes);
    } else {
        spmm_quad_kernel<<<row_blocks, threads, 0, stream>>>(
            x, indptr, indices, values, out, n_nodes);
    }
}

// Round 15
// 53.104 us; speedup vs baseline: 11.3717x; 1.2285x over previous
//
#include <hip/hip_runtime.h>
#include <hip/hip_fp16.h>

#define DIM 64

// ---------- pass 1: compress x (f32) -> xh (fp16) in workspace ----------
__global__ __launch_bounds__(256) void cvt_half_kernel(
    const float* __restrict__ x, __half* __restrict__ xh, int n4)
{
    int i = blockIdx.x * blockDim.x + threadIdx.x;
    const int stride = gridDim.x * blockDim.x;
    for (; i < n4; i += stride) {
        const float4 v = ((const float4*)x)[i];
        __half2 h0 = __floats2half2_rn(v.x, v.y);
        __half2 h1 = __floats2half2_rn(v.z, v.w);
        uint2 u;
        u.x = *(const unsigned int*)&h0;
        u.y = *(const unsigned int*)&h1;
        ((uint2*)xh)[i] = u;
    }
}

// ---------- pass 2: CSR SpMM over fp16 x (champion, R8 structure) ----------
// One wave per row. 8 groups x 8 lanes; group g owns edge slots k+g and
// k+8+g; lane reads 16B (8 halves) of that edge's x-row -> one dwordx4
// moves 8 edges' rows (1 KiB, 1 cache line per edge). Indices clamped to
// the row's own last edge (duplicate gathers coalesce to the same line).
__global__ __launch_bounds__(256) void spmm_half_kernel(
    const __half* __restrict__ xh,
    const int*   __restrict__ indptr,
    const int*   __restrict__ indices,
    const float* __restrict__ values,
    float*       __restrict__ out,
    int n_nodes)
{
    const int row  = (int)((blockIdx.x * blockDim.x + threadIdx.x) >> 6);
    const int lane = (int)(threadIdx.x & 63);
    if (row >= n_nodes) return;
    const int g = lane >> 3;        // edge slot 0..7
    const int t = lane & 7;         // column octet: cols [t*8, t*8+8)

    const int start = indptr[row];
    const int end   = indptr[row + 1];

    float a[8] = {0.f,0.f,0.f,0.f,0.f,0.f,0.f,0.f};

    if (start < end) {
        const int last = end - 1;
        for (int k = start; k < end; k += 16) {
            const int e0 = k + g;
            const int e1 = k + 8 + g;
            const int i0 = (e0 <= last) ? e0 : last;
            const int i1 = (e1 <= last) ? e1 : last;
            const int c0 = indices[i0];
            const int c1 = indices[i1];
            const float w0 = (e0 <= last) ? values[i0] : 0.0f;
            const float w1 = (e1 <= last) ? values[i1] : 0.0f;

            const uint4 p0 = *(const uint4*)(xh + (((unsigned)c0) << 6) + (t << 3));
            const uint4 p1 = *(const uint4*)(xh + (((unsigned)c1) << 6) + (t << 3));

            const __half* h0 = (const __half*)&p0;
            const __half* h1 = (const __half*)&p1;
#pragma unroll
            for (int j = 0; j < 8; ++j) a[j] += __half2float(h0[j]) * w0;
#pragma unroll
            for (int j = 0; j < 8; ++j) a[j] += __half2float(h1[j]) * w1;
        }
    }

    // Sum the 8 edge-groups: lanes {l^8, l^16, l^32} hold the same columns.
#define RED(m) a[0]+=__shfl_xor(a[0],m); a[1]+=__shfl_xor(a[1],m); \
               a[2]+=__shfl_xor(a[2],m); a[3]+=__shfl_xor(a[3],m); \
               a[4]+=__shfl_xor(a[4],m); a[5]+=__shfl_xor(a[5],m); \
               a[6]+=__shfl_xor(a[6],m); a[7]+=__shfl_xor(a[7],m);
    RED(8) RED(16) RED(32)
#undef RED

    if (lane < 8) {
        float4 r0; r0.x=a[0]; r0.y=a[1]; r0.z=a[2]; r0.w=a[3];
        float4 r1; r1.x=a[4]; r1.y=a[5]; r1.z=a[6]; r1.w=a[7];
        float* dst = out + (((size_t)row) << 6) + (t << 3);
        *(float4*)(dst)     = r0;
        *(float4*)(dst + 4) = r1;
    }
}

// ---------- f32 fallback (ws too small): round-3 quad kernel ----------
__global__ __launch_bounds__(256) void spmm_quad_kernel(
    const float* __restrict__ x,
    const int*   __restrict__ indptr,
    const int*   __restrict__ indices,
    const float* __restrict__ values,
    float*       __restrict__ out,
    int n_nodes)
{
    const int row  = (int)((blockIdx.x * blockDim.x + threadIdx.x) >> 6);
    const int lane = (int)(threadIdx.x & 63);
    if (row >= n_nodes) return;

    const int start = indptr[row];
    const int end   = indptr[row + 1];
    const int g     = lane >> 4;
    const unsigned col4 = (unsigned)(lane & 15) << 2;

    float ax = 0.f, ay = 0.f, az = 0.f, aw = 0.f;

    if (start < end) {
        const int last = end - 1;
        for (int k = start; k < end; k += 16) {
            const int e0 = k + 0 + g, e1 = k + 4 + g, e2 = k + 8 + g, e3 = k + 12 + g;
            const int ce0 = e0 <= last ? e0 : last;
            const int ce1 = e1 <= last ? e1 : last;
            const int ce2 = e2 <= last ? e2 : last;
            const int ce3 = e3 <= last ? e3 : last;
            const int c0 = indices[ce0], c1 = indices[ce1];
            const int c2 = indices[ce2], c3 = indices[ce3];
            const float w0 = (e0 <= last) ? values[ce0] : 0.0f;
            const float w1 = (e1 <= last) ? values[ce1] : 0.0f;
            const float w2 = (e2 <= last) ? values[ce2] : 0.0f;
            const float w3 = (e3 <= last) ? values[ce3] : 0.0f;
            const float4 a0 = *(const float4*)(x + (((unsigned)c0) << 6) + col4);
            const float4 a1 = *(const float4*)(x + (((unsigned)c1) << 6) + col4);
            const float4 a2 = *(const float4*)(x + (((unsigned)c2) << 6) + col4);
            const float4 a3 = *(const float4*)(x + (((unsigned)c3) << 6) + col4);
            ax += w0 * a0.x; ay += w0 * a0.y; az += w0 * a0.z; aw += w0 * a0.w;
            ax += w1 * a1.x; ay += w1 * a1.y; az += w1 * a1.z; aw += w1 * a1.w;
            ax += w2 * a2.x; ay += w2 * a2.y; az += w2 * a2.z; aw += w2 * a2.w;
            ax += w3 * a3.x; ay += w3 * a3.y; az += w3 * a3.z; aw += w3 * a3.w;
        }
    }

    ax += __shfl_xor(ax, 16); ay += __shfl_xor(ay, 16);
    az += __shfl_xor(az, 16); aw += __shfl_xor(aw, 16);
    ax += __shfl_xor(ax, 32); ay += __shfl_xor(ay, 32);
    az += __shfl_xor(az, 32); aw += __shfl_xor(aw, 32);

    if (lane < 16) {
        float4 r; r.x = ax; r.y = ay; r.z = az; r.w = aw;
        *(float4*)(out + ((size_t)row << 6) + col4) = r;
    }
}

extern "C" void kernel_launch(void* const* d_in, const int* in_sizes, int n_in,
                              void* d_out, int out_size, void* d_ws, size_t ws_size,
                              hipStream_t stream) {
    const float* x       = (const float*)d_in[0];
    const int*   indptr  = (const int*)  d_in[1];
    const int*   indices = (const int*)  d_in[2];
    const float* values  = (const float*)d_in[3];
    float*       out     = (float*)d_out;

    const int n_nodes = in_sizes[1] - 1;     // indptr has N+1 entries
    const int n_xelem = in_sizes[0];         // N * 64

    const int threads = 256;
    const int row_blocks = (n_nodes + 3) / 4;    // 4 waves/block, 1 row/wave

    const size_t xh_bytes = (size_t)n_xelem * sizeof(__half);
    if (ws_size >= xh_bytes) {
        __half* xh = (__half*)d_ws;
        cvt_half_kernel<<<2048, threads, 0, stream>>>(x, xh, n_xelem / 4);
        spmm_half_kernel<<<row_blocks, threads, 0, stream>>>(
            xh, indptr, indices, values, out, n_nodes);
    } else {
        spmm_quad_kernel<<<row_blocks, threads, 0, stream>>>(
            x, indptr, indices, values, out, n_nodes);
    }
}